// Round 1
// baseline (1715.256 us; speedup 1.0000x reference)
//
#include <hip/hip_runtime.h>
#include <hip/hip_bf16.h>

#define B_ 4
#define T_ 2048
#define C_ 1024

typedef unsigned short u16;
typedef unsigned int u32;

__device__ __forceinline__ float bf2f(u16 u) {
    union { float f; u32 i; } c; c.i = ((u32)u) << 16; return c.f;
}
__device__ __forceinline__ u16 f2bf(float f) {
    union { float f; u32 i; } c; c.f = f;
    u32 r = (c.i + 0x7FFFu + ((c.i >> 16) & 1u)) >> 16;
    return (u16)r;
}

// ---------------- Kernel 1: q/k/v = x @ W + b, stored bf16 -----------------
// grid (N/64=16, M/64=128, 3), block 256. M = B*T = 8192, N = K = 1024.
__global__ __launch_bounds__(256) void qkv_gemm(
    const float* __restrict__ X,
    const float* __restrict__ Wq, const float* __restrict__ bq,
    const float* __restrict__ Wk, const float* __restrict__ bk,
    const float* __restrict__ Wv, const float* __restrict__ bv,
    u16* __restrict__ qo, u16* __restrict__ ko, u16* __restrict__ vo)
{
    const int N = C_, K = C_;
    const float* W; const float* bias; u16* out;
    if (blockIdx.z == 0)      { W = Wq; bias = bq; out = qo; }
    else if (blockIdx.z == 1) { W = Wk; bias = bk; out = ko; }
    else                      { W = Wv; bias = bv; out = vo; }

    const int n0 = blockIdx.x * 64;
    const int m0 = blockIdx.y * 64;
    __shared__ float As[16][65];   // As[k][m]
    __shared__ float Bs[16][64];   // Bs[k][n]
    const int tid = threadIdx.x;
    const int tx = tid & 15, ty = tid >> 4;
    float acc[4][4] = {};

    for (int k0 = 0; k0 < K; k0 += 16) {
        {   // A tile 64x16
            int idx = tid * 4;
            int row = idx >> 4, col = idx & 15;
            float4 a4 = *(const float4*)(X + (size_t)(m0 + row) * K + k0 + col);
            As[col + 0][row] = a4.x; As[col + 1][row] = a4.y;
            As[col + 2][row] = a4.z; As[col + 3][row] = a4.w;
        }
        {   // B tile 16x64
            int idx = tid * 4;
            int row = idx >> 6, col = idx & 63;
            float4 b4 = *(const float4*)(W + (size_t)(k0 + row) * N + n0 + col);
            *(float4*)&Bs[row][col] = b4;
        }
        __syncthreads();
#pragma unroll
        for (int kk = 0; kk < 16; ++kk) {
            float a[4], b[4];
#pragma unroll
            for (int i = 0; i < 4; ++i) a[i] = As[kk][ty * 4 + i];
#pragma unroll
            for (int j = 0; j < 4; ++j) b[j] = Bs[kk][tx * 4 + j];
#pragma unroll
            for (int i = 0; i < 4; ++i)
#pragma unroll
                for (int j = 0; j < 4; ++j) acc[i][j] += a[i] * b[j];
        }
        __syncthreads();
    }
#pragma unroll
    for (int i = 0; i < 4; ++i) {
        int m = m0 + ty * 4 + i;
        ushort4 pk;
        pk.x = f2bf(acc[i][0] + bias[n0 + tx * 4 + 0]);
        pk.y = f2bf(acc[i][1] + bias[n0 + tx * 4 + 1]);
        pk.z = f2bf(acc[i][2] + bias[n0 + tx * 4 + 2]);
        pk.w = f2bf(acc[i][3] + bias[n0 + tx * 4 + 3]);
        *(ushort4*)(out + (size_t)m * N + n0 + tx * 4) = pk;
    }
}

// ------------- Kernel 2: S = q k^T * scale, causal, exp, rowsum ------------
// grid (T/64=32 s-tiles, T/64=32 m-tiles, B=4), block 256.
__global__ __launch_bounds__(256) void scores_kernel(
    const u16* __restrict__ qb, const u16* __restrict__ kb,
    u16* __restrict__ att, float* __restrict__ lsum)
{
    const int b = blockIdx.z;
    const int m0 = blockIdx.y * 64;
    const int s0 = blockIdx.x * 64;
    if (s0 > m0 + 63) return;   // fully above diagonal
    const u16* Q = qb + (size_t)b * T_ * C_;
    const u16* Km = kb + (size_t)b * T_ * C_;
    __shared__ float As[16][65];   // As[k][m]  (q)
    __shared__ float Bs[16][65];   // Bs[k][s]  (k, transposed)
    const int tid = threadIdx.x;
    const int tx = tid & 15, ty = tid >> 4;
    float acc[4][4] = {};

    for (int k0 = 0; k0 < C_; k0 += 16) {
        int idx = tid * 4;
        int row = idx >> 4, col = idx & 15;
        ushort4 a4 = *(const ushort4*)(Q + (size_t)(m0 + row) * C_ + k0 + col);
        As[col + 0][row] = bf2f(a4.x); As[col + 1][row] = bf2f(a4.y);
        As[col + 2][row] = bf2f(a4.z); As[col + 3][row] = bf2f(a4.w);
        ushort4 b4 = *(const ushort4*)(Km + (size_t)(s0 + row) * C_ + k0 + col);
        Bs[col + 0][row] = bf2f(b4.x); Bs[col + 1][row] = bf2f(b4.y);
        Bs[col + 2][row] = bf2f(b4.z); Bs[col + 3][row] = bf2f(b4.w);
        __syncthreads();
#pragma unroll
        for (int kk = 0; kk < 16; ++kk) {
            float a[4], bv2[4];
#pragma unroll
            for (int i = 0; i < 4; ++i) a[i] = As[kk][ty * 4 + i];
#pragma unroll
            for (int j = 0; j < 4; ++j) bv2[j] = Bs[kk][tx * 4 + j];
#pragma unroll
            for (int i = 0; i < 4; ++i)
#pragma unroll
                for (int j = 0; j < 4; ++j) acc[i][j] += a[i] * bv2[j];
        }
        __syncthreads();
    }

    const float scale = 0.03125f;   // 1/sqrt(1024)
#pragma unroll
    for (int i = 0; i < 4; ++i) {
        const int m = m0 + ty * 4 + i;
        float rs = 0.f;
        ushort4 pk;
        u16* pp = (u16*)&pk;
#pragma unroll
        for (int j = 0; j < 4; ++j) {
            const int s = s0 + tx * 4 + j;
            float e = 0.f;
            if (s <= m) e = __expf(acc[i][j] * scale);
            rs += e;
            pp[j] = f2bf(e);
        }
        *(ushort4*)(att + ((size_t)b * T_ + m) * T_ + s0 + tx * 4) = pk;
        // reduce row-sum across the 16 tx lanes (same ty -> same 16-lane group)
#pragma unroll
        for (int off = 8; off >= 1; off >>= 1) rs += __shfl_xor(rs, off, 16);
        if (tx == 0) atomicAdd(&lsum[b * T_ + m], rs);
    }
}

// --------------- Kernel 3: O = (P @ v) / l, fp32 out ----------------------
// grid (C/64=16, T/64=32, B=4), block 256.
__global__ __launch_bounds__(256) void pv_gemm(
    const u16* __restrict__ att, const u16* __restrict__ vb,
    const float* __restrict__ lsum, float* __restrict__ outp)
{
    const int b = blockIdx.z;
    const int n0 = blockIdx.x * 64;
    const int m0 = blockIdx.y * 64;
    const u16* A = att + (size_t)b * T_ * T_;
    const u16* V = vb + (size_t)b * T_ * C_;
    __shared__ float As[16][65];   // As[k][m]
    __shared__ float Bs[16][64];   // Bs[k][n]
    const int tid = threadIdx.x;
    const int tx = tid & 15, ty = tid >> 4;
    float acc[4][4] = {};

    const int Klim = m0 + 64;      // causal: P[m][s]=0 for s>m0+63
    for (int k0 = 0; k0 < Klim; k0 += 16) {
        {   // A tile 64x16 from att
            int idx = tid * 4;
            int row = idx >> 4, col = idx & 15;
            ushort4 a4 = *(const ushort4*)(A + (size_t)(m0 + row) * T_ + k0 + col);
            As[col + 0][row] = bf2f(a4.x); As[col + 1][row] = bf2f(a4.y);
            As[col + 2][row] = bf2f(a4.z); As[col + 3][row] = bf2f(a4.w);
        }
        {   // B tile 16x64 from v
            int idx = tid * 4;
            int row = idx >> 6, col = idx & 63;
            ushort4 b4 = *(const ushort4*)(V + (size_t)(k0 + row) * C_ + n0 + col);
            float4 f; f.x = bf2f(b4.x); f.y = bf2f(b4.y);
            f.z = bf2f(b4.z); f.w = bf2f(b4.w);
            *(float4*)&Bs[row][col] = f;
        }
        __syncthreads();
#pragma unroll
        for (int kk = 0; kk < 16; ++kk) {
            float a[4], bv2[4];
#pragma unroll
            for (int i = 0; i < 4; ++i) a[i] = As[kk][ty * 4 + i];
#pragma unroll
            for (int j = 0; j < 4; ++j) bv2[j] = Bs[kk][tx * 4 + j];
#pragma unroll
            for (int i = 0; i < 4; ++i)
#pragma unroll
                for (int j = 0; j < 4; ++j) acc[i][j] += a[i] * bv2[j];
        }
        __syncthreads();
    }
#pragma unroll
    for (int i = 0; i < 4; ++i) {
        const int m = m0 + ty * 4 + i;
        const float inv = 1.0f / lsum[b * T_ + m];
        float4 o;
        o.x = acc[i][0] * inv; o.y = acc[i][1] * inv;
        o.z = acc[i][2] * inv; o.w = acc[i][3] * inv;
        *(float4*)(outp + ((size_t)b * T_ + m) * C_ + n0 + tx * 4) = o;
    }
}

extern "C" void kernel_launch(void* const* d_in, const int* in_sizes, int n_in,
                              void* d_out, int out_size, void* d_ws, size_t ws_size,
                              hipStream_t stream) {
    const float* x  = (const float*)d_in[0];
    const float* Wq = (const float*)d_in[1];
    const float* bq = (const float*)d_in[2];
    const float* Wk = (const float*)d_in[3];
    const float* bk = (const float*)d_in[4];
    const float* Wv = (const float*)d_in[5];
    const float* bv = (const float*)d_in[6];
    float* out = (float*)d_out;

    char* ws = (char*)d_ws;
    u16* q    = (u16*)(ws);                        // 16 MB
    u16* k    = (u16*)(ws + (16ull << 20));        // 16 MB
    u16* v    = (u16*)(ws + (32ull << 20));        // 16 MB
    u16* att  = (u16*)(ws + (48ull << 20));        // 32 MB
    float* ls = (float*)(ws + (80ull << 20));      // 32 KB row sums

    hipMemsetAsync(ls, 0, B_ * T_ * sizeof(float), stream);
    qkv_gemm<<<dim3(16, 128, 3), 256, 0, stream>>>(x, Wq, bq, Wk, bk, Wv, bv, q, k, v);
    scores_kernel<<<dim3(32, 32, 4), 256, 0, stream>>>(q, k, att, ls);
    pv_gemm<<<dim3(16, 32, 4), 256, 0, stream>>>(att, v, ls, out);
}

// Round 2
// 328.792 us; speedup vs baseline: 5.2168x; 5.2168x over previous
//
#include <hip/hip_runtime.h>

#define B_ 4
#define T_ 2048
#define C_ 1024

typedef unsigned short u16;
typedef unsigned int u32;
typedef short sh8 __attribute__((ext_vector_type(8)));   // 8 bf16 payload (4 VGPRs)
typedef float f32x4 __attribute__((ext_vector_type(4)));

__device__ __forceinline__ float bf2f(u16 u) {
    union { float f; u32 i; } c; c.i = ((u32)u) << 16; return c.f;
}
__device__ __forceinline__ u16 f2bf(float f) {
    union { float f; u32 i; } c; c.f = f;
    return (u16)((c.i + 0x7FFFu + ((c.i >> 16) & 1u)) >> 16);
}

// async 16B/lane global->LDS. Dest = wave-uniform base + lane*16.
__device__ __forceinline__ void gload_lds16(const void* g, void* l) {
    __builtin_amdgcn_global_load_lds(
        (const __attribute__((address_space(1))) u32*)g,
        (__attribute__((address_space(3))) u32*)l, 16, 0, 0);
}

// ---------------------------------------------------------------------------
// Shared 128x128 TN MFMA core: C[m][n] = sum_k A[m][k]*B[n][k], bf16, BK=32.
// LDS layout per tile: 128 rows x 4 granules(16B), phys granule p = r*4 + (c ^ (r&3))
// (XOR swizzle -> conflict-free ds_read_b128 fragment loads; swizzle applied for
// free by permuting which lane loads which global granule in global_load_lds.)
// ---------------------------------------------------------------------------
__device__ __forceinline__ void mm_core(
    const u16* __restrict__ A, const u16* __restrict__ B,
    int ldA, int ldB, int nk,
    u16* lA, u16* lB, f32x4 (&acc)[4][4], int tid)
{
    const int w  = tid >> 6, l = tid & 63;
    const int fr = l & 15,  fq = l >> 4;
    const int wm = (w & 1) << 6, wn = (w >> 1) << 6;
    const int rl = l >> 2, cl = l & 3;

    for (int kt = 0; kt < nk; ++kt) {
        const int ko = kt << 5;
#pragma unroll
        for (int t = 0; t < 2; ++t) {
            const int r0 = t * 64 + w * 16;       // 16 rows per wave-instr
            const int r  = r0 + rl;
            const int cg = cl ^ (r & 3);          // logical granule for this lane
            gload_lds16(A + (size_t)r * ldA + ko + cg * 8, lA + (size_t)(r0 * 4 + l) * 8);
            gload_lds16(B + (size_t)r * ldB + ko + cg * 8, lB + (size_t)(r0 * 4 + l) * 8);
        }
        __syncthreads();
        sh8 af[4], bf[4];
#pragma unroll
        for (int i = 0; i < 4; ++i) {
            const int m = wm + i * 16 + fr;
            af[i] = *(const sh8*)(lA + (size_t)(m * 4 + (fq ^ (m & 3))) * 8);
            const int n = wn + i * 16 + fr;
            bf[i] = *(const sh8*)(lB + (size_t)(n * 4 + (fq ^ (n & 3))) * 8);
        }
#pragma unroll
        for (int i = 0; i < 4; ++i)
#pragma unroll
            for (int j = 0; j < 4; ++j)
                acc[i][j] = __builtin_amdgcn_mfma_f32_16x16x32_bf16(af[i], bf[j], acc[i][j], 0, 0, 0);
        __syncthreads();
    }
}

// --------------------- conversions -----------------------------------------
__global__ __launch_bounds__(256) void cvt_x(const float* __restrict__ x, u16* __restrict__ xb)
{
    size_t i = ((size_t)blockIdx.x * 256 + threadIdx.x) * 4;
    float4 f = *(const float4*)(x + i);
    ushort4 o;
    o.x = f2bf(f.x); o.y = f2bf(f.y); o.z = f2bf(f.z); o.w = f2bf(f.w);
    *(ushort4*)(xb + i) = o;
}

// W [K][N] fp32 -> Wt [N][K] bf16 (three weight matrices)
__global__ __launch_bounds__(256) void cvt_wt(
    const float* __restrict__ Wq, const float* __restrict__ Wk, const float* __restrict__ Wv,
    u16* __restrict__ wt)
{
    __shared__ float tile[64][68];
    const int z = blockIdx.z;
    const float* W = z == 0 ? Wq : (z == 1 ? Wk : Wv);
    u16* out = wt + (size_t)z * C_ * C_;
    const int n0 = blockIdx.x * 64, k0 = blockIdx.y * 64;
    const int tx = threadIdx.x & 15, ty = threadIdx.x >> 4;
#pragma unroll
    for (int rr = 0; rr < 4; ++rr) {
        int row = ty + rr * 16;
        *(float4*)&tile[row][tx * 4] = *(const float4*)(W + (size_t)(k0 + row) * C_ + n0 + tx * 4);
    }
    __syncthreads();
#pragma unroll
    for (int rr = 0; rr < 4; ++rr) {
        int n = ty + rr * 16;
        ushort4 o;
        o.x = f2bf(tile[tx * 4 + 0][n]);
        o.y = f2bf(tile[tx * 4 + 1][n]);
        o.z = f2bf(tile[tx * 4 + 2][n]);
        o.w = f2bf(tile[tx * 4 + 3][n]);
        *(ushort4*)(out + (size_t)(n0 + n) * C_ + k0 + tx * 4) = o;
    }
}

// --------------------- q/k/v projections ------------------------------------
// grid (8, 64, 3): n-tiles, m-tiles (M=B*T=8192), z in {q,k,v}.
// z==2 (v) writes TRANSPOSED: vt[b][c][t], via LDS bounce.
__global__ __launch_bounds__(256) void qkv_mfma(
    const u16* __restrict__ xb, const u16* __restrict__ wt,
    const float* __restrict__ bq, const float* __restrict__ bk, const float* __restrict__ bv,
    u16* __restrict__ qo, u16* __restrict__ ko, u16* __restrict__ vto)
{
    __shared__ __align__(16) u16 smem[16512];   // 33KB: staging (16KB) then 128x129 bounce
    u16* lA = smem; u16* lB = smem + 4096;
    const int z = blockIdx.z;
    const u16* W = wt + (size_t)z * C_ * C_;
    const float* bias = z == 0 ? bq : (z == 1 ? bk : bv);
    const int n0 = blockIdx.x * 128, m0 = blockIdx.y * 128;
    const int tid = threadIdx.x;
    f32x4 acc[4][4];
#pragma unroll
    for (int i = 0; i < 4; ++i)
#pragma unroll
        for (int j = 0; j < 4; ++j) acc[i][j] = 0.0f;

    mm_core(xb + (size_t)m0 * C_, W + (size_t)n0 * C_, C_, C_, C_ / 32, lA, lB, acc, tid);

    const int w = tid >> 6, l = tid & 63, fr = l & 15, fq = l >> 4;
    const int wm = (w & 1) << 6, wn = (w >> 1) << 6;
    if (z < 2) {
        u16* out = z == 0 ? qo : ko;
#pragma unroll
        for (int i = 0; i < 4; ++i)
#pragma unroll
            for (int j = 0; j < 4; ++j) {
                const int n = n0 + wn + j * 16 + fr;
                const float bb = bias[n];
#pragma unroll
                for (int r = 0; r < 4; ++r) {
                    const int m = m0 + wm + i * 16 + fq * 4 + r;
                    out[(size_t)m * C_ + n] = f2bf(acc[i][j][r] + bb);
                }
            }
    } else {
        // bounce through LDS to store v transposed with coalesced rows
#pragma unroll
        for (int i = 0; i < 4; ++i)
#pragma unroll
            for (int j = 0; j < 4; ++j) {
                const int ln = wn + j * 16 + fr;
                const float bb = bias[n0 + ln];
#pragma unroll
                for (int r = 0; r < 4; ++r) {
                    const int lm = wm + i * 16 + fq * 4 + r;
                    smem[lm * 129 + ln] = f2bf(acc[i][j][r] + bb);
                }
            }
        __syncthreads();
        const int b = m0 >> 11;          // batch
        const int t0 = m0 & 2047;        // position within batch
        u16* vt = vto + (size_t)b * C_ * T_;
#pragma unroll
        for (int pass = 0; pass < 8; ++pass) {
            const int ln = (tid >> 4) + pass * 16;   // local n (row of vt)
            const int c  = tid & 15;                 // 8-elem chunk along t
            u16 tmp[8];
#pragma unroll
            for (int e = 0; e < 8; ++e) tmp[e] = smem[(c * 8 + e) * 129 + ln];
            *(uint4*)(vt + (size_t)(n0 + ln) * T_ + t0 + c * 8) = *(uint4*)tmp;
        }
    }
}

// --------------------- scores: P = exp(q k^T / 32) (causal), rowsums --------
// grid (16, 16, 2), two passes of 2 batches; att buffer holds one batch pair.
__global__ __launch_bounds__(256) void scores_mfma(
    const u16* __restrict__ qb, const u16* __restrict__ kb,
    u16* __restrict__ attp, float* __restrict__ lsum, int pass)
{
    const int bx = blockIdx.x, by = blockIdx.y;
    if (bx > by) return;                         // strictly above diagonal
    const int b = pass * 2 + blockIdx.z;
    const int s0 = bx * 128, m0 = by * 128;
    __shared__ __align__(16) u16 smem[8192];
    u16* lA = smem; u16* lB = smem + 4096;
    const u16* Q = qb + (size_t)b * T_ * C_ + (size_t)m0 * C_;
    const u16* K = kb + (size_t)b * T_ * C_ + (size_t)s0 * C_;
    const int tid = threadIdx.x;
    f32x4 acc[4][4];
#pragma unroll
    for (int i = 0; i < 4; ++i)
#pragma unroll
        for (int j = 0; j < 4; ++j) acc[i][j] = 0.0f;

    mm_core(Q, K, C_, C_, C_ / 32, lA, lB, acc, tid);

    const int w = tid >> 6, l = tid & 63, fr = l & 15, fq = l >> 4;
    const int wm = (w & 1) << 6, wn = (w >> 1) << 6;
    u16* att = attp + (size_t)blockIdx.z * T_ * T_;
    float* ls = lsum + b * T_;
#pragma unroll
    for (int i = 0; i < 4; ++i)
#pragma unroll
        for (int r = 0; r < 4; ++r) {
            const int m = m0 + wm + i * 16 + fq * 4 + r;
            float rs = 0.f;
#pragma unroll
            for (int j = 0; j < 4; ++j) {
                const int s = s0 + wn + j * 16 + fr;
                float e = (s <= m) ? __expf(acc[i][j][r] * 0.03125f) : 0.f;
                att[(size_t)m * T_ + s] = f2bf(e);
                rs += e;
            }
#pragma unroll
            for (int off = 8; off >= 1; off >>= 1) rs += __shfl_xor(rs, off, 16);
            if (fr == 0) atomicAdd(ls + m, rs);
        }
}

// --------------------- O = (P v) / rowsum -----------------------------------
// grid (8, 16, 2). A = P [m][s] (ld T_), B = vt [n][s] (ld T_), K = m0+128.
__global__ __launch_bounds__(256) void pv_mfma(
    const u16* __restrict__ attp, const u16* __restrict__ vt,
    const float* __restrict__ lsum, float* __restrict__ outp, int pass)
{
    const int b = pass * 2 + blockIdx.z;
    const int n0 = blockIdx.x * 128, m0 = blockIdx.y * 128;
    __shared__ __align__(16) u16 smem[8192];
    u16* lA = smem; u16* lB = smem + 4096;
    const u16* A  = attp + (size_t)blockIdx.z * T_ * T_ + (size_t)m0 * T_;
    const u16* Bp = vt + (size_t)b * C_ * T_ + (size_t)n0 * T_;
    const int tid = threadIdx.x;
    f32x4 acc[4][4];
#pragma unroll
    for (int i = 0; i < 4; ++i)
#pragma unroll
        for (int j = 0; j < 4; ++j) acc[i][j] = 0.0f;

    mm_core(A, Bp, T_, T_, (m0 + 128) >> 5, lA, lB, acc, tid);

    const int w = tid >> 6, l = tid & 63, fr = l & 15, fq = l >> 4;
    const int wm = (w & 1) << 6, wn = (w >> 1) << 6;
#pragma unroll
    for (int i = 0; i < 4; ++i)
#pragma unroll
        for (int r = 0; r < 4; ++r) {
            const int m = m0 + wm + i * 16 + fq * 4 + r;
            const float inv = 1.0f / lsum[b * T_ + m];
#pragma unroll
            for (int j = 0; j < 4; ++j)
                outp[((size_t)b * T_ + m) * C_ + n0 + wn + j * 16 + fr] = acc[i][j][r] * inv;
        }
}

extern "C" void kernel_launch(void* const* d_in, const int* in_sizes, int n_in,
                              void* d_out, int out_size, void* d_ws, size_t ws_size,
                              hipStream_t stream) {
    const float* x  = (const float*)d_in[0];
    const float* Wq = (const float*)d_in[1];
    const float* bq = (const float*)d_in[2];
    const float* Wk = (const float*)d_in[3];
    const float* bk = (const float*)d_in[4];
    const float* Wv = (const float*)d_in[5];
    const float* bv = (const float*)d_in[6];
    float* out = (float*)d_out;

    // workspace layout (total 80 MB, with dead-region overlays):
    //   [ 0,16M)  xb  (bf16 x)          -- dead after qkv; lsum reuses offset 0
    //   [16,32M)  q
    //   [32,48M)  k
    //   [48,64M)  vt  (v transposed [b][c][t])
    //   [64,70M)  wt  (bf16 W^T x3)     -- dead after qkv
    //   [64,80M)  attp (P for a 2-batch pair) -- reuses wt region
    char* ws = (char*)d_ws;
    u16* xb   = (u16*)ws;
    u16* q    = (u16*)(ws + (16ull << 20));
    u16* k    = (u16*)(ws + (32ull << 20));
    u16* vt   = (u16*)(ws + (48ull << 20));
    u16* wt   = (u16*)(ws + (64ull << 20));
    u16* attp = (u16*)(ws + (64ull << 20));
    float* ls = (float*)ws;

    cvt_x  <<<8192, 256, 0, stream>>>(x, xb);
    cvt_wt <<<dim3(16, 16, 3), 256, 0, stream>>>(Wq, Wk, Wv, wt);
    qkv_mfma<<<dim3(8, 64, 3), 256, 0, stream>>>(xb, wt, bq, bk, bv, q, k, vt);
    hipMemsetAsync(ls, 0, B_ * T_ * sizeof(float), stream);
    for (int p = 0; p < 2; ++p) {
        scores_mfma<<<dim3(16, 16, 2), 256, 0, stream>>>(q, k, attp, ls, p);
        pv_mfma    <<<dim3(8, 16, 2), 256, 0, stream>>>(attp, vt, ls, out, p);
    }
}

// Round 3
// 280.086 us; speedup vs baseline: 6.1240x; 1.1739x over previous
//
#include <hip/hip_runtime.h>

#define B_ 4
#define T_ 2048
#define C_ 1024

typedef unsigned short u16;
typedef unsigned int u32;
typedef short sh8 __attribute__((ext_vector_type(8)));   // 8 bf16 payload (4 VGPRs)
typedef float f32x4 __attribute__((ext_vector_type(4)));

__device__ __forceinline__ float bf2f(u16 u) {
    union { float f; u32 i; } c; c.i = ((u32)u) << 16; return c.f;
}
__device__ __forceinline__ u16 f2bf(float f) {
    union { float f; u32 i; } c; c.f = f;
    return (u16)((c.i + 0x7FFFu + ((c.i >> 16) & 1u)) >> 16);
}

// async 16B/lane global->LDS. Dest = wave-uniform base + lane*16.
__device__ __forceinline__ void gload_lds16(const void* g, void* l) {
    __builtin_amdgcn_global_load_lds(
        (const __attribute__((address_space(1))) u32*)g,
        (__attribute__((address_space(3))) u32*)l, 16, 0, 0);
}

// ---------------------------------------------------------------------------
// Shared 128x128 TN MFMA core: C[m][n] = sum_k A[m][k]*B[n][k], bf16, BK=32.
// XOR-swizzled LDS granules -> conflict-free ds_read_b128; swizzle applied in
// the lane->global mapping of global_load_lds (free).
// RS: also accumulate row-sums of A via MFMA against a ones-fragment.
// ---------------------------------------------------------------------------
template<bool RS>
__device__ __forceinline__ void mm_core(
    const u16* __restrict__ A, const u16* __restrict__ B,
    int ldA, int ldB, int nk,
    u16* lA, u16* lB, f32x4 (&acc)[4][4], f32x4* rsacc, int tid)
{
    const int w  = tid >> 6, l = tid & 63;
    const int fr = l & 15,  fq = l >> 4;
    const int wm = (w & 1) << 6, wn = (w >> 1) << 6;
    const int rl = l >> 2, cl = l & 3;

    sh8 ones;
    if (RS) {
#pragma unroll
        for (int e = 0; e < 8; ++e) ones[e] = (short)0x3F80;  // bf16 1.0
    }

    for (int kt = 0; kt < nk; ++kt) {
        const int ko = kt << 5;
#pragma unroll
        for (int t = 0; t < 2; ++t) {
            const int r0 = t * 64 + w * 16;       // 16 rows per wave-instr
            const int r  = r0 + rl;
            const int cg = cl ^ (r & 3);          // logical granule for this lane
            gload_lds16(A + (size_t)r * ldA + ko + cg * 8, lA + (size_t)(r0 * 4 + l) * 8);
            gload_lds16(B + (size_t)r * ldB + ko + cg * 8, lB + (size_t)(r0 * 4 + l) * 8);
        }
        __syncthreads();
        sh8 af[4], bf[4];
#pragma unroll
        for (int i = 0; i < 4; ++i) {
            const int m = wm + i * 16 + fr;
            af[i] = *(const sh8*)(lA + (size_t)(m * 4 + (fq ^ (m & 3))) * 8);
            const int n = wn + i * 16 + fr;
            bf[i] = *(const sh8*)(lB + (size_t)(n * 4 + (fq ^ (n & 3))) * 8);
        }
#pragma unroll
        for (int i = 0; i < 4; ++i) {
#pragma unroll
            for (int j = 0; j < 4; ++j)
                acc[i][j] = __builtin_amdgcn_mfma_f32_16x16x32_bf16(af[i], bf[j], acc[i][j], 0, 0, 0);
            if (RS)
                rsacc[i] = __builtin_amdgcn_mfma_f32_16x16x32_bf16(af[i], ones, rsacc[i], 0, 0, 0);
        }
        __syncthreads();
    }
}

// --------------------- conversions (fused) ----------------------------------
// blocks [0,8192): x fp32 -> bf16.  blocks [8192,8960): W -> W^T bf16 (x3).
__global__ __launch_bounds__(256) void cvt_all(
    const float* __restrict__ x,
    const float* __restrict__ Wq, const float* __restrict__ Wk, const float* __restrict__ Wv,
    u16* __restrict__ xb, u16* __restrict__ wt)
{
    __shared__ float tile[64][68];
    const int bid = blockIdx.x;
    if (bid < 8192) {
        size_t i = ((size_t)bid * 256 + threadIdx.x) * 4;
        float4 f = *(const float4*)(x + i);
        ushort4 o;
        o.x = f2bf(f.x); o.y = f2bf(f.y); o.z = f2bf(f.z); o.w = f2bf(f.w);
        *(ushort4*)(xb + i) = o;
        return;
    }
    const int r = bid - 8192;
    const int z = r >> 8;                  // 0..2
    const int rr = r & 255;
    const int n0 = (rr & 15) * 64, k0 = (rr >> 4) * 64;
    const float* W = z == 0 ? Wq : (z == 1 ? Wk : Wv);
    u16* out = wt + (size_t)z * C_ * C_;
    const int tx = threadIdx.x & 15, ty = threadIdx.x >> 4;
#pragma unroll
    for (int rr2 = 0; rr2 < 4; ++rr2) {
        int row = ty + rr2 * 16;
        *(float4*)&tile[row][tx * 4] = *(const float4*)(W + (size_t)(k0 + row) * C_ + n0 + tx * 4);
    }
    __syncthreads();
#pragma unroll
    for (int rr2 = 0; rr2 < 4; ++rr2) {
        int n = ty + rr2 * 16;
        ushort4 o;
        o.x = f2bf(tile[tx * 4 + 0][n]);
        o.y = f2bf(tile[tx * 4 + 1][n]);
        o.z = f2bf(tile[tx * 4 + 2][n]);
        o.w = f2bf(tile[tx * 4 + 3][n]);
        *(ushort4*)(out + (size_t)(n0 + n) * C_ + k0 + tx * 4) = o;
    }
}

// --------------------- q/k/v projections ------------------------------------
// grid (8, 64, 3). z==2 (v) writes TRANSPOSED vt[b][c][t] via LDS bounce.
__global__ __launch_bounds__(256) void qkv_mfma(
    const u16* __restrict__ xb, const u16* __restrict__ wt,
    const float* __restrict__ bq, const float* __restrict__ bk, const float* __restrict__ bv,
    u16* __restrict__ qo, u16* __restrict__ ko, u16* __restrict__ vto)
{
    __shared__ __align__(16) u16 smem[16512];   // staging 16KB; bounce 128x129
    u16* lA = smem; u16* lB = smem + 4096;
    const int z = blockIdx.z;
    const u16* W = wt + (size_t)z * C_ * C_;
    const float* bias = z == 0 ? bq : (z == 1 ? bk : bv);
    const int n0 = blockIdx.x * 128, m0 = blockIdx.y * 128;
    const int tid = threadIdx.x;
    f32x4 acc[4][4];
#pragma unroll
    for (int i = 0; i < 4; ++i)
#pragma unroll
        for (int j = 0; j < 4; ++j) acc[i][j] = 0.0f;

    mm_core<false>(xb + (size_t)m0 * C_, W + (size_t)n0 * C_, C_, C_, C_ / 32, lA, lB, acc, nullptr, tid);

    const int w = tid >> 6, l = tid & 63, fr = l & 15, fq = l >> 4;
    const int wm = (w & 1) << 6, wn = (w >> 1) << 6;
    if (z < 2) {
        u16* out = z == 0 ? qo : ko;
#pragma unroll
        for (int i = 0; i < 4; ++i)
#pragma unroll
            for (int j = 0; j < 4; ++j) {
                const int n = n0 + wn + j * 16 + fr;
                const float bb = bias[n];
#pragma unroll
                for (int r = 0; r < 4; ++r) {
                    const int m = m0 + wm + i * 16 + fq * 4 + r;
                    out[(size_t)m * C_ + n] = f2bf(acc[i][j][r] + bb);
                }
            }
    } else {
        __syncthreads();
#pragma unroll
        for (int i = 0; i < 4; ++i)
#pragma unroll
            for (int j = 0; j < 4; ++j) {
                const int ln = wn + j * 16 + fr;
                const float bb = bias[n0 + ln];
#pragma unroll
                for (int r = 0; r < 4; ++r) {
                    const int lm = wm + i * 16 + fq * 4 + r;
                    smem[lm * 129 + ln] = f2bf(acc[i][j][r] + bb);
                }
            }
        __syncthreads();
        const int b = m0 >> 11;
        const int t0 = m0 & 2047;
        u16* vt = vto + (size_t)b * C_ * T_;
#pragma unroll
        for (int pass = 0; pass < 8; ++pass) {
            const int ln = (tid >> 4) + pass * 16;
            const int c  = tid & 15;
            u16 tmp[8];
#pragma unroll
            for (int e = 0; e < 8; ++e) tmp[e] = smem[(c * 8 + e) * 129 + ln];
            *(uint4*)(vt + (size_t)(n0 + ln) * T_ + t0 + c * 8) = *(uint4*)tmp;
        }
    }
}

// att per-batch offsets in u16 units: b0,b1 over xb region; b2,b3 over wt region.
__device__ __constant__ size_t att_off[4] = {
    0, (size_t)1 << 22, (size_t)1 << 25, ((size_t)1 << 25) + ((size_t)1 << 22)
};

// --------------------- scores: P = exp(q k^T / 32), causal ------------------
// grid (136, 1, 4): flattened lower-triangle tile index x batch.
__global__ __launch_bounds__(256) void scores_mfma(
    const u16* __restrict__ qb, const u16* __restrict__ kb, u16* __restrict__ wsbase)
{
    int t = blockIdx.x;
    int by = (int)((sqrtf(8.f * t + 1.f) - 1.f) * 0.5f);
    while ((by + 1) * (by + 2) / 2 <= t) ++by;
    while (by * (by + 1) / 2 > t) --by;
    const int bx = t - by * (by + 1) / 2;
    const int b = blockIdx.z;
    const int s0 = bx * 128, m0 = by * 128;
    __shared__ __align__(16) u16 smem[8192];
    u16* lA = smem; u16* lB = smem + 4096;
    const u16* Q = qb + (size_t)b * T_ * C_ + (size_t)m0 * C_;
    const u16* K = kb + (size_t)b * T_ * C_ + (size_t)s0 * C_;
    const int tid = threadIdx.x;
    f32x4 acc[4][4];
#pragma unroll
    for (int i = 0; i < 4; ++i)
#pragma unroll
        for (int j = 0; j < 4; ++j) acc[i][j] = 0.0f;

    mm_core<false>(Q, K, C_, C_, C_ / 32, lA, lB, acc, nullptr, tid);

    const int w = tid >> 6, l = tid & 63, fr = l & 15, fq = l >> 4;
    const int wm = (w & 1) << 6, wn = (w >> 1) << 6;
    u16* att = wsbase + att_off[b];
#pragma unroll
    for (int i = 0; i < 4; ++i)
#pragma unroll
        for (int r = 0; r < 4; ++r) {
            const int m = m0 + wm + i * 16 + fq * 4 + r;
#pragma unroll
            for (int j = 0; j < 4; ++j) {
                const int s = s0 + wn + j * 16 + fr;
                float e = (s <= m) ? __expf(acc[i][j][r] * 0.03125f) : 0.f;
                att[(size_t)m * T_ + s] = f2bf(e);
            }
        }
}

// --------------------- O = (P v) / rowsum -----------------------------------
// grid (8, 16, 4), heavy m-tiles first. Rowsum via MFMA-with-ones in mm_core.
__global__ __launch_bounds__(256) void pv_mfma(
    const u16* __restrict__ wsbase, const u16* __restrict__ vt,
    float* __restrict__ outp)
{
    const int b = blockIdx.z;
    const int n0 = blockIdx.x * 128;
    const int by = 15 - blockIdx.y;            // heavy (long-K) tiles dispatch first
    const int m0 = by * 128;
    __shared__ __align__(16) u16 smem[8192];
    u16* lA = smem; u16* lB = smem + 4096;
    const u16* A  = wsbase + att_off[b] + (size_t)m0 * T_;
    const u16* Bp = vt + (size_t)b * C_ * T_ + (size_t)n0 * T_;
    const int tid = threadIdx.x;
    f32x4 acc[4][4], rs[4];
#pragma unroll
    for (int i = 0; i < 4; ++i) {
        rs[i] = 0.0f;
#pragma unroll
        for (int j = 0; j < 4; ++j) acc[i][j] = 0.0f;
    }

    mm_core<true>(A, Bp, T_, T_, (m0 + 128) >> 5, lA, lB, acc, rs, tid);

    const int w = tid >> 6, l = tid & 63, fr = l & 15, fq = l >> 4;
    const int wm = (w & 1) << 6, wn = (w >> 1) << 6;
#pragma unroll
    for (int i = 0; i < 4; ++i)
#pragma unroll
        for (int r = 0; r < 4; ++r) {
            const int m = m0 + wm + i * 16 + fq * 4 + r;
            const float inv = 1.0f / rs[i][r];
#pragma unroll
            for (int j = 0; j < 4; ++j)
                outp[((size_t)b * T_ + m) * C_ + n0 + wn + j * 16 + fr] = acc[i][j][r] * inv;
        }
}

extern "C" void kernel_launch(void* const* d_in, const int* in_sizes, int n_in,
                              void* d_out, int out_size, void* d_ws, size_t ws_size,
                              hipStream_t stream) {
    const float* x  = (const float*)d_in[0];
    const float* Wq = (const float*)d_in[1];
    const float* bq = (const float*)d_in[2];
    const float* Wk = (const float*)d_in[3];
    const float* bk = (const float*)d_in[4];
    const float* Wv = (const float*)d_in[5];
    const float* bv = (const float*)d_in[6];
    float* out = (float*)d_out;

    // workspace (80 MB):
    //   [ 0,16M) xb   -> dead after qkv; att batches 0,1 overlay
    //   [16,32M) q
    //   [32,48M) k
    //   [48,64M) vt   (v transposed [b][c][t])
    //   [64,70M) wt   -> dead after qkv; att batches 2,3 overlay [64,80M)
    char* ws = (char*)d_ws;
    u16* xb   = (u16*)ws;
    u16* q    = (u16*)(ws + (16ull << 20));
    u16* k    = (u16*)(ws + (32ull << 20));
    u16* vt   = (u16*)(ws + (48ull << 20));
    u16* wt   = (u16*)(ws + (64ull << 20));
    u16* attb = (u16*)ws;   // att_off[] indexes from workspace base

    cvt_all <<<8960, 256, 0, stream>>>(x, Wq, Wk, Wv, xb, wt);
    qkv_mfma<<<dim3(8, 64, 3), 256, 0, stream>>>(xb, wt, bq, bk, bv, q, k, vt);
    scores_mfma<<<dim3(136, 1, 4), 256, 0, stream>>>(q, k, attb);
    pv_mfma    <<<dim3(8, 16, 4), 256, 0, stream>>>(attb, vt, out);
}

// Round 4
// 279.043 us; speedup vs baseline: 6.1469x; 1.0037x over previous
//
#include <hip/hip_runtime.h>

#define B_ 4
#define T_ 2048
#define C_ 1024

typedef unsigned short u16;
typedef unsigned int u32;
typedef short sh8 __attribute__((ext_vector_type(8)));   // 8 bf16 payload (4 VGPRs)
typedef float f32x4 __attribute__((ext_vector_type(4)));

__device__ __forceinline__ float bf2f(u16 u) {
    union { float f; u32 i; } c; c.i = ((u32)u) << 16; return c.f;
}
__device__ __forceinline__ u16 f2bf(float f) {
    union { float f; u32 i; } c; c.f = f;
    return (u16)((c.i + 0x7FFFu + ((c.i >> 16) & 1u)) >> 16);
}

// async 16B/lane global->LDS. Dest = wave-uniform base + lane*16.
__device__ __forceinline__ void gload_lds16(const void* g, void* l) {
    __builtin_amdgcn_global_load_lds(
        (const __attribute__((address_space(1))) u32*)g,
        (__attribute__((address_space(3))) u32*)l, 16, 0, 0);
}

// ---------------------------------------------------------------------------
// Shared 128x128 TN MFMA core: C[m][n] = sum_k A[m][k]*B[n][k], bf16, BK=32.
// XOR-swizzled LDS granules -> conflict-free ds_read_b128; swizzle applied in
// the lane->global mapping of global_load_lds (free).
// RS: also accumulate row-sums of A via MFMA against a ones-fragment.
// ---------------------------------------------------------------------------
template<bool RS>
__device__ __forceinline__ void mm_core(
    const u16* __restrict__ A, const u16* __restrict__ B,
    int ldA, int ldB, int nk,
    u16* lA, u16* lB, f32x4 (&acc)[4][4], f32x4* rsacc, int tid)
{
    const int w  = tid >> 6, l = tid & 63;
    const int fr = l & 15,  fq = l >> 4;
    const int wm = (w & 1) << 6, wn = (w >> 1) << 6;
    const int rl = l >> 2, cl = l & 3;

    sh8 ones;
    if (RS) {
#pragma unroll
        for (int e = 0; e < 8; ++e) ones[e] = (short)0x3F80;  // bf16 1.0
    }

    for (int kt = 0; kt < nk; ++kt) {
        const int ko = kt << 5;
#pragma unroll
        for (int t = 0; t < 2; ++t) {
            const int r0 = t * 64 + w * 16;       // 16 rows per wave-instr
            const int r  = r0 + rl;
            const int cg = cl ^ (r & 3);          // logical granule for this lane
            gload_lds16(A + (size_t)r * ldA + ko + cg * 8, lA + (size_t)(r0 * 4 + l) * 8);
            gload_lds16(B + (size_t)r * ldB + ko + cg * 8, lB + (size_t)(r0 * 4 + l) * 8);
        }
        __syncthreads();
        sh8 af[4], bf[4];
#pragma unroll
        for (int i = 0; i < 4; ++i) {
            const int m = wm + i * 16 + fr;
            af[i] = *(const sh8*)(lA + (size_t)(m * 4 + (fq ^ (m & 3))) * 8);
            const int n = wn + i * 16 + fr;
            bf[i] = *(const sh8*)(lB + (size_t)(n * 4 + (fq ^ (n & 3))) * 8);
        }
#pragma unroll
        for (int i = 0; i < 4; ++i) {
#pragma unroll
            for (int j = 0; j < 4; ++j)
                acc[i][j] = __builtin_amdgcn_mfma_f32_16x16x32_bf16(af[i], bf[j], acc[i][j], 0, 0, 0);
            if (RS)
                rsacc[i] = __builtin_amdgcn_mfma_f32_16x16x32_bf16(af[i], ones, rsacc[i], 0, 0, 0);
        }
        __syncthreads();
    }
}

// --------------------- conversions (fused) ----------------------------------
// blocks [0,8192): x fp32 -> bf16.  blocks [8192,8960): W -> W^T bf16 (x3).
__global__ __launch_bounds__(256) void cvt_all(
    const float* __restrict__ x,
    const float* __restrict__ Wq, const float* __restrict__ Wk, const float* __restrict__ Wv,
    u16* __restrict__ xb, u16* __restrict__ wt)
{
    __shared__ float tile[64][68];
    const int bid = blockIdx.x;
    if (bid < 8192) {
        size_t i = ((size_t)bid * 256 + threadIdx.x) * 4;
        float4 f = *(const float4*)(x + i);
        ushort4 o;
        o.x = f2bf(f.x); o.y = f2bf(f.y); o.z = f2bf(f.z); o.w = f2bf(f.w);
        *(ushort4*)(xb + i) = o;
        return;
    }
    const int r = bid - 8192;
    const int z = r >> 8;                  // 0..2
    const int rr = r & 255;
    const int n0 = (rr & 15) * 64, k0 = (rr >> 4) * 64;
    const float* W = z == 0 ? Wq : (z == 1 ? Wk : Wv);
    u16* out = wt + (size_t)z * C_ * C_;
    const int tx = threadIdx.x & 15, ty = threadIdx.x >> 4;
#pragma unroll
    for (int rr2 = 0; rr2 < 4; ++rr2) {
        int row = ty + rr2 * 16;
        *(float4*)&tile[row][tx * 4] = *(const float4*)(W + (size_t)(k0 + row) * C_ + n0 + tx * 4);
    }
    __syncthreads();
#pragma unroll
    for (int rr2 = 0; rr2 < 4; ++rr2) {
        int n = ty + rr2 * 16;
        ushort4 o;
        o.x = f2bf(tile[tx * 4 + 0][n]);
        o.y = f2bf(tile[tx * 4 + 1][n]);
        o.z = f2bf(tile[tx * 4 + 2][n]);
        o.w = f2bf(tile[tx * 4 + 3][n]);
        *(ushort4*)(out + (size_t)(n0 + n) * C_ + k0 + tx * 4) = o;
    }
}

// --------------------- q/k/v projections ------------------------------------
// grid (8, 64, 3). z==2 (v) writes TRANSPOSED vt[b][c][t] via LDS bounce.
// q/k epilogue: LDS bounce (128x136 u16) -> coalesced uint4 stores.
__global__ __launch_bounds__(256) void qkv_mfma(
    const u16* __restrict__ xb, const u16* __restrict__ wt,
    const float* __restrict__ bq, const float* __restrict__ bk, const float* __restrict__ bv,
    u16* __restrict__ qo, u16* __restrict__ ko, u16* __restrict__ vto)
{
    __shared__ __align__(16) u16 smem[17408];   // 34 KB: staging 16KB | bounce
    u16* lA = smem; u16* lB = smem + 4096;
    const int z = blockIdx.z;
    const u16* W = wt + (size_t)z * C_ * C_;
    const float* bias = z == 0 ? bq : (z == 1 ? bk : bv);
    const int n0 = blockIdx.x * 128, m0 = blockIdx.y * 128;
    const int tid = threadIdx.x;
    f32x4 acc[4][4];
#pragma unroll
    for (int i = 0; i < 4; ++i)
#pragma unroll
        for (int j = 0; j < 4; ++j) acc[i][j] = 0.0f;

    mm_core<false>(xb + (size_t)m0 * C_, W + (size_t)n0 * C_, C_, C_, C_ / 32, lA, lB, acc, nullptr, tid);

    const int w = tid >> 6, l = tid & 63, fr = l & 15, fq = l >> 4;
    const int wm = (w & 1) << 6, wn = (w >> 1) << 6;
    if (z < 2) {
        // bounce to LDS, then wide coalesced stores
#pragma unroll
        for (int i = 0; i < 4; ++i)
#pragma unroll
            for (int j = 0; j < 4; ++j) {
                const int ln = wn + j * 16 + fr;
                const float bb = bias[n0 + ln];
#pragma unroll
                for (int r = 0; r < 4; ++r) {
                    const int lm = wm + i * 16 + fq * 4 + r;
                    smem[lm * 136 + ln] = f2bf(acc[i][j][r] + bb);
                }
            }
        __syncthreads();
        u16* out = z == 0 ? qo : ko;
        const int rr = tid >> 4, cc = tid & 15;
#pragma unroll
        for (int p = 0; p < 8; ++p) {
            const int row = p * 16 + rr;
            uint4 val = *(const uint4*)&smem[row * 136 + cc * 8];
            *(uint4*)(out + (size_t)(m0 + row) * C_ + n0 + cc * 8) = val;
        }
    } else {
        // bounce through LDS to store v transposed with coalesced rows
#pragma unroll
        for (int i = 0; i < 4; ++i)
#pragma unroll
            for (int j = 0; j < 4; ++j) {
                const int ln = wn + j * 16 + fr;
                const float bb = bias[n0 + ln];
#pragma unroll
                for (int r = 0; r < 4; ++r) {
                    const int lm = wm + i * 16 + fq * 4 + r;
                    smem[lm * 129 + ln] = f2bf(acc[i][j][r] + bb);
                }
            }
        __syncthreads();
        const int b = m0 >> 11;
        const int t0 = m0 & 2047;
        u16* vt = vto + (size_t)b * C_ * T_;
#pragma unroll
        for (int pass = 0; pass < 8; ++pass) {
            const int ln = (tid >> 4) + pass * 16;
            const int c  = tid & 15;
            u16 tmp[8];
#pragma unroll
            for (int e = 0; e < 8; ++e) tmp[e] = smem[(c * 8 + e) * 129 + ln];
            *(uint4*)(vt + (size_t)(n0 + ln) * T_ + t0 + c * 8) = *(uint4*)tmp;
        }
    }
}

// att per-batch offsets in u16 units: b0,b1 over xb region; b2,b3 over wt region.
__device__ __constant__ size_t att_off[4] = {
    0, (size_t)1 << 22, (size_t)1 << 25, ((size_t)1 << 25) + ((size_t)1 << 22)
};

// --------------------- scores: P = exp(q k^T / 32), causal ------------------
// grid (136, 1, 4): flattened lower-triangle tile index x batch.
__global__ __launch_bounds__(256) void scores_mfma(
    const u16* __restrict__ qb, const u16* __restrict__ kb, u16* __restrict__ wsbase)
{
    int t = blockIdx.x;
    int by = (int)((sqrtf(8.f * t + 1.f) - 1.f) * 0.5f);
    while ((by + 1) * (by + 2) / 2 <= t) ++by;
    while (by * (by + 1) / 2 > t) --by;
    const int bx = t - by * (by + 1) / 2;
    const int b = blockIdx.z;
    const int s0 = bx * 128, m0 = by * 128;
    __shared__ __align__(16) u16 smem[17408];
    u16* lA = smem; u16* lB = smem + 4096;
    const u16* Q = qb + (size_t)b * T_ * C_ + (size_t)m0 * C_;
    const u16* K = kb + (size_t)b * T_ * C_ + (size_t)s0 * C_;
    const int tid = threadIdx.x;
    f32x4 acc[4][4];
#pragma unroll
    for (int i = 0; i < 4; ++i)
#pragma unroll
        for (int j = 0; j < 4; ++j) acc[i][j] = 0.0f;

    mm_core<false>(Q, K, C_, C_, C_ / 32, lA, lB, acc, nullptr, tid);

    const int w = tid >> 6, l = tid & 63, fr = l & 15, fq = l >> 4;
    const int wm = (w & 1) << 6, wn = (w >> 1) << 6;
#pragma unroll
    for (int i = 0; i < 4; ++i)
#pragma unroll
        for (int r = 0; r < 4; ++r) {
            const int lm = wm + i * 16 + fq * 4 + r;
            const int m = m0 + lm;
#pragma unroll
            for (int j = 0; j < 4; ++j) {
                const int ls = wn + j * 16 + fr;
                const int s = s0 + ls;
                float e = (s <= m) ? __expf(acc[i][j][r] * 0.03125f) : 0.f;
                smem[lm * 136 + ls] = f2bf(e);
            }
        }
    __syncthreads();
    u16* att = wsbase + att_off[b] + (size_t)m0 * T_ + s0;
    const int rr = tid >> 4, cc = tid & 15;
#pragma unroll
    for (int p = 0; p < 8; ++p) {
        const int row = p * 16 + rr;
        uint4 val = *(const uint4*)&smem[row * 136 + cc * 8];
        *(uint4*)(att + (size_t)row * T_ + cc * 8) = val;
    }
}

// --------------------- O = (P v) / rowsum -----------------------------------
// grid (8, 16, 4), heavy m-tiles first. Rowsum via MFMA-with-ones in mm_core.
// Epilogue: two 64-row passes through f32 LDS bounce -> coalesced float4.
__global__ __launch_bounds__(256) void pv_mfma(
    const u16* __restrict__ wsbase, const u16* __restrict__ vt,
    float* __restrict__ outp)
{
    const int b = blockIdx.z;
    const int n0 = blockIdx.x * 128;
    const int by = 15 - blockIdx.y;            // heavy (long-K) tiles dispatch first
    const int m0 = by * 128;
    __shared__ __align__(16) u16 smem[17408];
    u16* lA = smem; u16* lB = smem + 4096;
    const u16* A  = wsbase + att_off[b] + (size_t)m0 * T_;
    const u16* Bp = vt + (size_t)b * C_ * T_ + (size_t)n0 * T_;
    const int tid = threadIdx.x;
    f32x4 acc[4][4], rs[4];
#pragma unroll
    for (int i = 0; i < 4; ++i) {
        rs[i] = 0.0f;
#pragma unroll
        for (int j = 0; j < 4; ++j) acc[i][j] = 0.0f;
    }

    mm_core<true>(A, Bp, T_, T_, (m0 + 128) >> 5, lA, lB, acc, rs, tid);

    const int w = tid >> 6, l = tid & 63, fr = l & 15, fq = l >> 4;
    const int wm = (w & 1) << 6, wn = (w >> 1) << 6;
    float* fb = (float*)smem;                  // 64 x 132 f32 bounce
#pragma unroll
    for (int p = 0; p < 2; ++p) {
        if ((w & 1) == p) {
#pragma unroll
            for (int i = 0; i < 4; ++i)
#pragma unroll
                for (int r = 0; r < 4; ++r) {
                    const int rr2 = i * 16 + fq * 4 + r;
                    const float inv = 1.0f / rs[i][r];
#pragma unroll
                    for (int j = 0; j < 4; ++j)
                        fb[rr2 * 132 + wn + j * 16 + fr] = acc[i][j][r] * inv;
                }
        }
        __syncthreads();
        const int rr = tid >> 5, cc = (tid & 31) * 4;
#pragma unroll
        for (int k2 = 0; k2 < 8; ++k2) {
            const int row = k2 * 8 + rr;
            float4 val = *(const float4*)&fb[row * 132 + cc];
            *(float4*)(outp + ((size_t)b * T_ + m0 + p * 64 + row) * C_ + n0 + cc) = val;
        }
        __syncthreads();
    }
}

extern "C" void kernel_launch(void* const* d_in, const int* in_sizes, int n_in,
                              void* d_out, int out_size, void* d_ws, size_t ws_size,
                              hipStream_t stream) {
    const float* x  = (const float*)d_in[0];
    const float* Wq = (const float*)d_in[1];
    const float* bq = (const float*)d_in[2];
    const float* Wk = (const float*)d_in[3];
    const float* bk = (const float*)d_in[4];
    const float* Wv = (const float*)d_in[5];
    const float* bv = (const float*)d_in[6];
    float* out = (float*)d_out;

    // workspace (80 MB):
    //   [ 0,16M) xb   -> dead after qkv; att batches 0,1 overlay
    //   [16,32M) q
    //   [32,48M) k
    //   [48,64M) vt   (v transposed [b][c][t])
    //   [64,70M) wt   -> dead after qkv; att batches 2,3 overlay [64,80M)
    char* ws = (char*)d_ws;
    u16* xb   = (u16*)ws;
    u16* q    = (u16*)(ws + (16ull << 20));
    u16* k    = (u16*)(ws + (32ull << 20));
    u16* vt   = (u16*)(ws + (48ull << 20));
    u16* wt   = (u16*)(ws + (64ull << 20));
    u16* attb = (u16*)ws;   // att_off[] indexes from workspace base

    cvt_all <<<8960, 256, 0, stream>>>(x, Wq, Wk, Wv, xb, wt);
    qkv_mfma<<<dim3(8, 64, 3), 256, 0, stream>>>(xb, wt, bq, bk, bv, q, k, vt);
    scores_mfma<<<dim3(136, 1, 4), 256, 0, stream>>>(q, k, attb);
    pv_mfma    <<<dim3(8, 16, 4), 256, 0, stream>>>(attb, vt, out);
}

// Round 5
// 250.253 us; speedup vs baseline: 6.8541x; 1.1150x over previous
//
#include <hip/hip_runtime.h>

#define B_ 4
#define T_ 2048
#define C_ 1024

typedef unsigned short u16;
typedef unsigned int u32;
typedef short sh8 __attribute__((ext_vector_type(8)));   // 8 bf16 payload (4 VGPRs)
typedef float f32x4 __attribute__((ext_vector_type(4)));

__device__ __forceinline__ float bf2f(u16 u) {
    union { float f; u32 i; } c; c.i = ((u32)u) << 16; return c.f;
}
__device__ __forceinline__ u16 f2bf(float f) {
    union { float f; u32 i; } c; c.f = f;
    return (u16)((c.i + 0x7FFFu + ((c.i >> 16) & 1u)) >> 16);
}

// async 16B/lane global->LDS. Dest = wave-uniform base + lane*16.
__device__ __forceinline__ void gload_lds16(const void* g, void* l) {
    __builtin_amdgcn_global_load_lds(
        (const __attribute__((address_space(1))) u32*)g,
        (__attribute__((address_space(3))) u32*)l, 16, 0, 0);
}

// ---------------------------------------------------------------------------
// Shared 128x128 TN MFMA core: C[m][n] = sum_k A[m][k]*B[n][k], bf16, BK=64.
// LDS tile: 128 rows x 8 granules(16B); phys col = c ^ (m&7).  Fragment reads
// then hit bank-quad (c^(m&7)) which sweeps all 8 quads across fr -> only the
// free 2-way aliasing remains (fr vs fr+8).  Swizzle applied for free in the
// lane->global-granule mapping of global_load_lds.
// 32 MFMAs between barriers (2 kk-steps of 16).
// RS: also accumulate row-sums of A via MFMA against a ones-fragment.
// ---------------------------------------------------------------------------
template<bool RS>
__device__ __forceinline__ void mm_core(
    const u16* __restrict__ A, const u16* __restrict__ B,
    int ldA, int ldB, int nk64,
    u16* lA, u16* lB, f32x4 (&acc)[4][4], f32x4* rsacc, int tid)
{
    const int w  = tid >> 6, l = tid & 63;
    const int fr = l & 15,  fq = l >> 4;
    const int wm = (w & 1) << 6, wn = (w >> 1) << 6;
    const int rl = l >> 3;            // 0..7: row within the 8-row group
    const int pc = l & 7;             // phys granule col this lane fills
    const int cg = pc ^ rl;           // logical granule to fetch (r&7 == rl)

    sh8 ones;
    if (RS) {
#pragma unroll
        for (int e = 0; e < 8; ++e) ones[e] = (short)0x3F80;  // bf16 1.0
    }

    for (int kt = 0; kt < nk64; ++kt) {
        const int ko = kt << 6;
#pragma unroll
        for (int t = 0; t < 4; ++t) {
            const int r0 = w * 32 + t * 8;        // 8 rows per wave-instr
            const int r  = r0 + rl;
            gload_lds16(A + (size_t)r * ldA + ko + cg * 8, lA + ((size_t)r0 * 8 + l) * 8);
            gload_lds16(B + (size_t)r * ldB + ko + cg * 8, lB + ((size_t)r0 * 8 + l) * 8);
        }
        __syncthreads();
#pragma unroll
        for (int kk = 0; kk < 2; ++kk) {
            sh8 af[4], bf[4];
            const int g = kk * 4 + fq;            // logical granule of this frag
#pragma unroll
            for (int i = 0; i < 4; ++i) {
                const int m = wm + i * 16 + fr;
                af[i] = *(const sh8*)(lA + ((size_t)m * 8 + (g ^ (m & 7))) * 8);
                const int n = wn + i * 16 + fr;
                bf[i] = *(const sh8*)(lB + ((size_t)n * 8 + (g ^ (n & 7))) * 8);
            }
#pragma unroll
            for (int i = 0; i < 4; ++i) {
#pragma unroll
                for (int j = 0; j < 4; ++j)
                    acc[i][j] = __builtin_amdgcn_mfma_f32_16x16x32_bf16(af[i], bf[j], acc[i][j], 0, 0, 0);
                if (RS)
                    rsacc[i] = __builtin_amdgcn_mfma_f32_16x16x32_bf16(af[i], ones, rsacc[i], 0, 0, 0);
            }
        }
        __syncthreads();
    }
}

// --------------------- conversions (fused) ----------------------------------
// blocks [0,8192): x fp32 -> bf16.  blocks [8192,8960): W -> W^T bf16 (x3).
__global__ __launch_bounds__(256) void cvt_all(
    const float* __restrict__ x,
    const float* __restrict__ Wq, const float* __restrict__ Wk, const float* __restrict__ Wv,
    u16* __restrict__ xb, u16* __restrict__ wt)
{
    __shared__ float tile[64][68];
    const int bid = blockIdx.x;
    if (bid < 8192) {
        size_t i = ((size_t)bid * 256 + threadIdx.x) * 4;
        float4 f = *(const float4*)(x + i);
        ushort4 o;
        o.x = f2bf(f.x); o.y = f2bf(f.y); o.z = f2bf(f.z); o.w = f2bf(f.w);
        *(ushort4*)(xb + i) = o;
        return;
    }
    const int r = bid - 8192;
    const int z = r >> 8;                  // 0..2
    const int rr = r & 255;
    const int n0 = (rr & 15) * 64, k0 = (rr >> 4) * 64;
    const float* W = z == 0 ? Wq : (z == 1 ? Wk : Wv);
    u16* out = wt + (size_t)z * C_ * C_;
    const int tx = threadIdx.x & 15, ty = threadIdx.x >> 4;
#pragma unroll
    for (int rr2 = 0; rr2 < 4; ++rr2) {
        int row = ty + rr2 * 16;
        *(float4*)&tile[row][tx * 4] = *(const float4*)(W + (size_t)(k0 + row) * C_ + n0 + tx * 4);
    }
    __syncthreads();
#pragma unroll
    for (int rr2 = 0; rr2 < 4; ++rr2) {
        int n = ty + rr2 * 16;
        ushort4 o;
        o.x = f2bf(tile[tx * 4 + 0][n]);
        o.y = f2bf(tile[tx * 4 + 1][n]);
        o.z = f2bf(tile[tx * 4 + 2][n]);
        o.w = f2bf(tile[tx * 4 + 3][n]);
        *(ushort4*)(out + (size_t)(n0 + n) * C_ + k0 + tx * 4) = o;
    }
}

// --------------------- q/k/v projections ------------------------------------
// grid (8, 64, 3). z==2 (v) writes TRANSPOSED vt[b][c][t] via LDS bounce.
// q/k epilogue: LDS bounce (128x136 u16) -> coalesced uint4 stores.
__global__ __launch_bounds__(256, 4) void qkv_mfma(
    const u16* __restrict__ xb, const u16* __restrict__ wt,
    const float* __restrict__ bq, const float* __restrict__ bk, const float* __restrict__ bv,
    u16* __restrict__ qo, u16* __restrict__ ko, u16* __restrict__ vto)
{
    __shared__ __align__(16) u16 smem[17408];   // 34 KB: staging 32KB | bounce
    u16* lA = smem; u16* lB = smem + 8192;
    const int z = blockIdx.z;
    const u16* W = wt + (size_t)z * C_ * C_;
    const float* bias = z == 0 ? bq : (z == 1 ? bk : bv);
    const int n0 = blockIdx.x * 128, m0 = blockIdx.y * 128;
    const int tid = threadIdx.x;
    f32x4 acc[4][4];
#pragma unroll
    for (int i = 0; i < 4; ++i)
#pragma unroll
        for (int j = 0; j < 4; ++j) acc[i][j] = 0.0f;

    mm_core<false>(xb + (size_t)m0 * C_, W + (size_t)n0 * C_, C_, C_, C_ / 64, lA, lB, acc, nullptr, tid);

    const int w = tid >> 6, l = tid & 63, fr = l & 15, fq = l >> 4;
    const int wm = (w & 1) << 6, wn = (w >> 1) << 6;
    if (z < 2) {
        // bounce to LDS, then wide coalesced stores
#pragma unroll
        for (int i = 0; i < 4; ++i)
#pragma unroll
            for (int j = 0; j < 4; ++j) {
                const int ln = wn + j * 16 + fr;
                const float bb = bias[n0 + ln];
#pragma unroll
                for (int r = 0; r < 4; ++r) {
                    const int lm = wm + i * 16 + fq * 4 + r;
                    smem[lm * 136 + ln] = f2bf(acc[i][j][r] + bb);
                }
            }
        __syncthreads();
        u16* out = z == 0 ? qo : ko;
        const int rr = tid >> 4, cc = tid & 15;
#pragma unroll
        for (int p = 0; p < 8; ++p) {
            const int row = p * 16 + rr;
            uint4 val = *(const uint4*)&smem[row * 136 + cc * 8];
            *(uint4*)(out + (size_t)(m0 + row) * C_ + n0 + cc * 8) = val;
        }
    } else {
        // bounce through LDS to store v transposed with coalesced rows
#pragma unroll
        for (int i = 0; i < 4; ++i)
#pragma unroll
            for (int j = 0; j < 4; ++j) {
                const int ln = wn + j * 16 + fr;
                const float bb = bias[n0 + ln];
#pragma unroll
                for (int r = 0; r < 4; ++r) {
                    const int lm = wm + i * 16 + fq * 4 + r;
                    smem[lm * 129 + ln] = f2bf(acc[i][j][r] + bb);
                }
            }
        __syncthreads();
        const int b = m0 >> 11;
        const int t0 = m0 & 2047;
        u16* vt = vto + (size_t)b * C_ * T_;
#pragma unroll
        for (int pass = 0; pass < 8; ++pass) {
            const int ln = (tid >> 4) + pass * 16;
            const int c  = tid & 15;
            u16 tmp[8];
#pragma unroll
            for (int e = 0; e < 8; ++e) tmp[e] = smem[(c * 8 + e) * 129 + ln];
            *(uint4*)(vt + (size_t)(n0 + ln) * T_ + t0 + c * 8) = *(uint4*)tmp;
        }
    }
}

// att per-batch offsets in u16 units: b0,b1 over xb region; b2,b3 over wt region.
__device__ __constant__ size_t att_off[4] = {
    0, (size_t)1 << 22, (size_t)1 << 25, ((size_t)1 << 25) + ((size_t)1 << 22)
};

// --------------------- scores: P = exp(q k^T / 32), causal ------------------
// grid (136, 1, 4): flattened lower-triangle tile index x batch.
__global__ __launch_bounds__(256, 4) void scores_mfma(
    const u16* __restrict__ qb, const u16* __restrict__ kb, u16* __restrict__ wsbase)
{
    int t = blockIdx.x;
    int by = (int)((sqrtf(8.f * t + 1.f) - 1.f) * 0.5f);
    while ((by + 1) * (by + 2) / 2 <= t) ++by;
    while (by * (by + 1) / 2 > t) --by;
    const int bx = t - by * (by + 1) / 2;
    const int b = blockIdx.z;
    const int s0 = bx * 128, m0 = by * 128;
    __shared__ __align__(16) u16 smem[17408];
    u16* lA = smem; u16* lB = smem + 8192;
    const u16* Q = qb + (size_t)b * T_ * C_ + (size_t)m0 * C_;
    const u16* K = kb + (size_t)b * T_ * C_ + (size_t)s0 * C_;
    const int tid = threadIdx.x;
    f32x4 acc[4][4];
#pragma unroll
    for (int i = 0; i < 4; ++i)
#pragma unroll
        for (int j = 0; j < 4; ++j) acc[i][j] = 0.0f;

    mm_core<false>(Q, K, C_, C_, C_ / 64, lA, lB, acc, nullptr, tid);

    const int w = tid >> 6, l = tid & 63, fr = l & 15, fq = l >> 4;
    const int wm = (w & 1) << 6, wn = (w >> 1) << 6;
#pragma unroll
    for (int i = 0; i < 4; ++i)
#pragma unroll
        for (int r = 0; r < 4; ++r) {
            const int lm = wm + i * 16 + fq * 4 + r;
            const int m = m0 + lm;
#pragma unroll
            for (int j = 0; j < 4; ++j) {
                const int ls = wn + j * 16 + fr;
                const int s = s0 + ls;
                float e = (s <= m) ? __expf(acc[i][j][r] * 0.03125f) : 0.f;
                smem[lm * 136 + ls] = f2bf(e);
            }
        }
    __syncthreads();
    u16* att = wsbase + att_off[b] + (size_t)m0 * T_ + s0;
    const int rr = tid >> 4, cc = tid & 15;
#pragma unroll
    for (int p = 0; p < 8; ++p) {
        const int row = p * 16 + rr;
        uint4 val = *(const uint4*)&smem[row * 136 + cc * 8];
        *(uint4*)(att + (size_t)row * T_ + cc * 8) = val;
    }
}

// --------------------- O = (P v) / rowsum -----------------------------------
// grid (8, 16, 4), heavy m-tiles first. Rowsum via MFMA-with-ones in mm_core.
// Epilogue: two 64-row passes through f32 LDS bounce -> coalesced float4.
__global__ __launch_bounds__(256, 4) void pv_mfma(
    const u16* __restrict__ wsbase, const u16* __restrict__ vt,
    float* __restrict__ outp)
{
    const int b = blockIdx.z;
    const int n0 = blockIdx.x * 128;
    const int by = 15 - blockIdx.y;            // heavy (long-K) tiles dispatch first
    const int m0 = by * 128;
    __shared__ __align__(16) u16 smem[17408];
    u16* lA = smem; u16* lB = smem + 8192;
    const u16* A  = wsbase + att_off[b] + (size_t)m0 * T_;
    const u16* Bp = vt + (size_t)b * C_ * T_ + (size_t)n0 * T_;
    const int tid = threadIdx.x;
    f32x4 acc[4][4], rs[4];
#pragma unroll
    for (int i = 0; i < 4; ++i) {
        rs[i] = 0.0f;
#pragma unroll
        for (int j = 0; j < 4; ++j) acc[i][j] = 0.0f;
    }

    mm_core<true>(A, Bp, T_, T_, (m0 + 128) >> 6, lA, lB, acc, rs, tid);

    const int w = tid >> 6, l = tid & 63, fr = l & 15, fq = l >> 4;
    const int wm = (w & 1) << 6, wn = (w >> 1) << 6;
    float* fb = (float*)smem;                  // 64 x 132 f32 bounce
#pragma unroll
    for (int p = 0; p < 2; ++p) {
        if ((w & 1) == p) {
#pragma unroll
            for (int i = 0; i < 4; ++i)
#pragma unroll
                for (int r = 0; r < 4; ++r) {
                    const int rr2 = i * 16 + fq * 4 + r;
                    const float inv = 1.0f / rs[i][r];
#pragma unroll
                    for (int j = 0; j < 4; ++j)
                        fb[rr2 * 132 + wn + j * 16 + fr] = acc[i][j][r] * inv;
                }
        }
        __syncthreads();
        const int rr = tid >> 5, cc = (tid & 31) * 4;
#pragma unroll
        for (int k2 = 0; k2 < 8; ++k2) {
            const int row = k2 * 8 + rr;
            float4 val = *(const float4*)&fb[row * 132 + cc];
            *(float4*)(outp + ((size_t)b * T_ + m0 + p * 64 + row) * C_ + n0 + cc) = val;
        }
        __syncthreads();
    }
}

extern "C" void kernel_launch(void* const* d_in, const int* in_sizes, int n_in,
                              void* d_out, int out_size, void* d_ws, size_t ws_size,
                              hipStream_t stream) {
    const float* x  = (const float*)d_in[0];
    const float* Wq = (const float*)d_in[1];
    const float* bq = (const float*)d_in[2];
    const float* Wk = (const float*)d_in[3];
    const float* bk = (const float*)d_in[4];
    const float* Wv = (const float*)d_in[5];
    const float* bv = (const float*)d_in[6];
    float* out = (float*)d_out;

    // workspace (80 MB):
    //   [ 0,16M) xb   -> dead after qkv; att batches 0,1 overlay
    //   [16,32M) q
    //   [32,48M) k
    //   [48,64M) vt   (v transposed [b][c][t])
    //   [64,70M) wt   -> dead after qkv; att batches 2,3 overlay [64,80M)
    char* ws = (char*)d_ws;
    u16* xb   = (u16*)ws;
    u16* q    = (u16*)(ws + (16ull << 20));
    u16* k    = (u16*)(ws + (32ull << 20));
    u16* vt   = (u16*)(ws + (48ull << 20));
    u16* wt   = (u16*)(ws + (64ull << 20));
    u16* attb = (u16*)ws;   // att_off[] indexes from workspace base

    cvt_all <<<8960, 256, 0, stream>>>(x, Wq, Wk, Wv, xb, wt);
    qkv_mfma<<<dim3(8, 64, 3), 256, 0, stream>>>(xb, wt, bq, bk, bv, q, k, vt);
    scores_mfma<<<dim3(136, 1, 4), 256, 0, stream>>>(q, k, attb);
    pv_mfma    <<<dim3(8, 16, 4), 256, 0, stream>>>(attb, vt, out);
}